// Round 7
// baseline (240.817 us; speedup 1.0000x reference)
//
#include <hip/hip_runtime.h>

// Fused attention with masked-key compaction, 6 dispatches, DENSE tile enumeration
// (R6 post-mortem: npad-gated early-exit blocks formed period-16/128 dead stripes
// that idled ~44% of CUs because the pattern period divides the 256-CU round-robin;
// grid-stride over a dense active-tile list fixes the stripe for any npad):
//  L1 prep:    cast x,W -> f16; per-batch mask scan (sel/counts/npad)
//  L2 gather:  xc[b][s'] = xh[b][sel[s']] (pad rows zeroed)
//  L3 qkvt:    dense enum {Q tiles(512), K tiles(8*mt per b), Vt tiles(8*mt)} G=1024
//  L4 s64:     S = (Q Kc^T)/32, M=64 tiles, dense enum (32*mt per b), G=1280 @5/CU
//  L5 softmax: compacted rows (cols>=counts -> -inf; pad cols -> 0)
//  L6 pv64:    O = P @ Vt^T (K=npad), M=64 tiles, 1024 tiles on G=1024 (4/CU even)
// GEMM cores: BK=64, global_load_lds w=16, XOR-swizzled LDS (0 bank conflicts, R2).
// 128-body: 4x4 16x16x32 MFMA/wave, 32KB LDS. 64-body: 2x4 MFMA/wave, 24KB LDS.

typedef _Float16 f16;
typedef _Float16 f16x4 __attribute__((ext_vector_type(4)));
typedef _Float16 f16x8 __attribute__((ext_vector_type(8)));
typedef float f32x4 __attribute__((ext_vector_type(4)));

#define LB256 __launch_bounds__(256)

__device__ __forceinline__ void gld16(const void* gp, void* lp) {
  __builtin_amdgcn_global_load_lds(
      (__attribute__((address_space(1))) void*)(gp),
      (__attribute__((address_space(3))) void*)(lp),
      16, 0, 0);
}

// ---------------------------------------------------------------- 128x128 GEMM body
// C[m,n] = scale * sum_k A[m,k]*B[n,k] + bias. bias_row=0: bias(col) split at nb1;
// bias_row=1: bias1(row). As/Bs: caller-provided 128*64 f16 LDS tiles.
template <typename OutT>
__device__ __forceinline__ void gemm_body(
    f16* As, f16* Bs,
    const f16* __restrict__ A, int lda, const f16* __restrict__ B, int ldb,
    OutT* __restrict__ C, int ldc,
    const float* __restrict__ bias1, const float* __restrict__ bias2, int nb1,
    int bias_row, float scale, int K, int m0, int n0) {
  const int tid = threadIdx.x;
  const int w = tid >> 6, l = tid & 63;
  const int wm = (w >> 1) * 64, wn = (w & 1) * 64;
  const int quad = l >> 4, lo = l & 15;
  const int rl = l >> 3;
  const int scol = ((l & 7) ^ rl) * 8;
  const int swz = (quad ^ (lo & 3)) * 8;
  const int ks0 = ((lo >> 2) & 1) * 32;

  f32x4 acc[4][4] = {};
  for (int kk = 0; kk < K; kk += 64) {
#pragma unroll
    for (int r = 0; r < 4; ++r) {
      const int c8 = r * 4 + w;
      const int row = c8 * 8 + rl;
      gld16(A + (long)(m0 + row) * lda + kk + scol, &As[c8 * 512]);
      gld16(B + (long)(n0 + row) * ldb + kk + scol, &Bs[c8 * 512]);
    }
    __syncthreads();
#pragma unroll
    for (int ks = 0; ks < 2; ++ks) {
      const int kso = ks ? (32 - ks0) : ks0;
      f16x8 af[4], bf[4];
#pragma unroll
      for (int i = 0; i < 4; ++i)
        af[i] = *(const f16x8*)&As[(wm + i * 16 + lo) * 64 + swz + kso];
#pragma unroll
      for (int j = 0; j < 4; ++j)
        bf[j] = *(const f16x8*)&Bs[(wn + j * 16 + lo) * 64 + swz + kso];
#pragma unroll
      for (int i = 0; i < 4; ++i)
#pragma unroll
        for (int j = 0; j < 4; ++j)
          acc[i][j] = __builtin_amdgcn_mfma_f32_16x16x32_f16(af[i], bf[j],
                                                             acc[i][j], 0, 0, 0);
    }
    __syncthreads();
  }
#pragma unroll
  for (int i = 0; i < 4; ++i) {
    const int rowb = m0 + wm + i * 16 + quad * 4;
#pragma unroll
    for (int j = 0; j < 4; ++j) {
      const int col = n0 + wn + j * 16 + lo;
      float bc = 0.f;
      if (bias1 && !bias_row) bc = (col < nb1) ? bias1[col] : bias2[col - nb1];
#pragma unroll
      for (int r = 0; r < 4; ++r) {
        float bv = bias_row ? bias1[rowb + r] : bc;
        C[(long)(rowb + r) * ldc + col] = (OutT)(acc[i][j][r] * scale + bv);
      }
    }
  }
}

// ---------------------------------------------------------------- 64x128 GEMM body
// M-tile 64, N-tile 128, BK=64. Wave grid 2x2: wm=(w>>1)*32, wn=(w&1)*64; 2x4 MFMA.
// Same XOR swizzle (row stride is 64 f16 in both tiles). No bias.
template <typename OutT>
__device__ __forceinline__ void gemm_body64(
    f16* As, f16* Bs,
    const f16* __restrict__ A, int lda, const f16* __restrict__ B, int ldb,
    OutT* __restrict__ C, int ldc, float scale, int K, int m0, int n0) {
  const int tid = threadIdx.x;
  const int w = tid >> 6, l = tid & 63;
  const int wm = (w >> 1) * 32, wn = (w & 1) * 64;
  const int quad = l >> 4, lo = l & 15;
  const int rl = l >> 3;
  const int scol = ((l & 7) ^ rl) * 8;
  const int swz = (quad ^ (lo & 3)) * 8;
  const int ks0 = ((lo >> 2) & 1) * 32;

  f32x4 acc[2][4] = {};
  for (int kk = 0; kk < K; kk += 64) {
    // A: 8 chunks (64 rows), wave w loads {2w,2w+1}; B: 16 chunks, wave w {4w..4w+3}.
#pragma unroll
    for (int r = 0; r < 2; ++r) {
      const int c8 = w * 2 + r;
      gld16(A + (long)(m0 + c8 * 8 + rl) * lda + kk + scol, &As[c8 * 512]);
    }
#pragma unroll
    for (int r = 0; r < 4; ++r) {
      const int c8 = w * 4 + r;
      gld16(B + (long)(n0 + c8 * 8 + rl) * ldb + kk + scol, &Bs[c8 * 512]);
    }
    __syncthreads();
#pragma unroll
    for (int ks = 0; ks < 2; ++ks) {
      const int kso = ks ? (32 - ks0) : ks0;
      f16x8 af[2], bf[4];
#pragma unroll
      for (int i = 0; i < 2; ++i)
        af[i] = *(const f16x8*)&As[(wm + i * 16 + lo) * 64 + swz + kso];
#pragma unroll
      for (int j = 0; j < 4; ++j)
        bf[j] = *(const f16x8*)&Bs[(wn + j * 16 + lo) * 64 + swz + kso];
#pragma unroll
      for (int i = 0; i < 2; ++i)
#pragma unroll
        for (int j = 0; j < 4; ++j)
          acc[i][j] = __builtin_amdgcn_mfma_f32_16x16x32_f16(af[i], bf[j],
                                                             acc[i][j], 0, 0, 0);
    }
    __syncthreads();
  }
#pragma unroll
  for (int i = 0; i < 2; ++i) {
    const int rowb = m0 + wm + i * 16 + quad * 4;
#pragma unroll
    for (int j = 0; j < 4; ++j) {
      const int col = n0 + wn + j * 16 + lo;
#pragma unroll
      for (int r = 0; r < 4; ++r)
        C[(long)(rowb + r) * ldc + col] = (OutT)(acc[i][j][r] * scale);
    }
  }
}

// ---------------------------------------------------------------- L1 prep
__global__ LB256 void prep(const float* __restrict__ x, const float* __restrict__ wq,
                           const float* __restrict__ wk, const float* __restrict__ wv,
                           const void* __restrict__ maskp, f16* __restrict__ xh,
                           f16* __restrict__ wh, int* __restrict__ sel,
                           int* __restrict__ counts, int* __restrict__ npad) {
  const int blk = blockIdx.x;
  const int t = threadIdx.x;
  if (blk < 11264) {
    long i = ((long)blk * 256 + t) * 4;
    const float* src;
    f16* dst;
    if (i < 8388608L) {
      src = x + i;
      dst = xh + i;
    } else {
      long j = i - 8388608L;
      int which = (int)(j >> 20);
      const float* ws = which == 0 ? wq : (which == 1 ? wk : wv);
      src = ws + (j & 1048575L);
      dst = wh + j;
    }
    float4 v = *(const float4*)src;
    f16x4 o;
    o[0] = (f16)v.x; o[1] = (f16)v.y; o[2] = (f16)v.z; o[3] = (f16)v.w;
    *(f16x4*)dst = o;
  } else {
    const int b = blk - 11264;
    __shared__ int bad;
    __shared__ int s[256];
    if (t == 0) bad = 0;
    __syncthreads();
    const int* mi = (const int*)maskp;
    int loc = 0;
    for (int i = t; i < 2048; i += 256)
      if ((unsigned)mi[i] > 1u) loc = 1;  // byte-packed bools look like big ints
    if (loc) atomicOr(&bad, 1);
    __syncthreads();
    const bool bytemode = bad != 0;
    int m[8];
    if (bytemode) {
      const unsigned char* p = (const unsigned char*)maskp + b * 2048 + t * 8;
#pragma unroll
      for (int e = 0; e < 8; ++e) m[e] = p[e] != 0;
    } else {
      const int* p = mi + b * 2048 + t * 8;
#pragma unroll
      for (int e = 0; e < 8; ++e) m[e] = p[e] != 0;
    }
    int local = 0;
#pragma unroll
    for (int e = 0; e < 8; ++e) local += m[e];
    s[t] = local;
    __syncthreads();
    for (int off = 1; off < 256; off <<= 1) {
      int v = (t >= off) ? s[t - off] : 0;
      __syncthreads();
      s[t] += v;
      __syncthreads();
    }
    int offp = s[t] - local;
#pragma unroll
    for (int e = 0; e < 8; ++e)
      if (m[e]) sel[b * 2048 + offp++] = t * 8 + e;
    if (t == 0) {
      counts[b] = s[255];
      npad[b] = ((s[255] + 127) >> 7) << 7;
    }
  }
}

// ---------------------------------------------------------------- L2 gather
__global__ LB256 void gather_x(const f16* __restrict__ xh, const int* __restrict__ sel,
                               const int* __restrict__ counts,
                               const int* __restrict__ npad, f16* __restrict__ xc) {
  const int b = blockIdx.y;
  const int np = npad[b], cnt = counts[b];
  const int t = threadIdx.x;
#pragma unroll
  for (int i = 0; i < 4; ++i) {
    const int sp = blockIdx.x * 4 + i;
    if (sp >= np) continue;
    f16* dst = xc + ((long)b * 2048 + sp) * 1024;
    if (sp >= cnt) {
      *(f16x4*)(dst + t * 4) = (f16x4){0, 0, 0, 0};
    } else {
      const f16* src = xh + ((long)b * 2048 + sel[b * 2048 + sp]) * 1024;
      *(f16x4*)(dst + t * 4) = *(const f16x4*)(src + t * 4);
    }
  }
}

// ---------------------------------------------------------------- L3 Q+K+Vt (dense)
// Tiles: [0,512): Q (M=8192,N=1024). Then per batch b: 8*mt K tiles (m-idx<mt,
// n-idx<8), then 8*mt Vt tiles (m-idx<8, n-idx<mt), mt = npad[b]/128.
__global__ __launch_bounds__(256, 4) void qkvt_gemm(
    const f16* __restrict__ xh, const f16* __restrict__ xc,
    const f16* __restrict__ Wh, f16* __restrict__ Qb, f16* __restrict__ Kc,
    f16* __restrict__ Vt, const float* __restrict__ bq,
    const float* __restrict__ bk, const float* __restrict__ bv,
    const int* __restrict__ npad) {
  __shared__ __align__(16) f16 As[128 * 64];
  __shared__ __align__(16) f16 Bs[128 * 64];
  int ku[4];
  int T = 512;
#pragma unroll
  for (int b = 0; b < 4; ++b) {
    ku[b] = 16 * (npad[b] >> 7);
    T += ku[b];
  }
  for (int tile = blockIdx.x; tile < T; tile += gridDim.x) {
    if (tile < 512) {
      gemm_body<f16>(As, Bs, xh, 1024, Wh, 1024, Qb, 1024, bq, bq, 1 << 30, 0,
                     1.0f, 1024, (tile >> 3) * 128, (tile & 7) * 128);
    } else {
      int u = tile - 512, b = 0;
      while (u >= ku[b]) { u -= ku[b]; ++b; }
      const int mt8 = ku[b] >> 1;  // 8*mt
      if (u < mt8) {  // K tile
        gemm_body<f16>(As, Bs, xc + (long)b * 2048 * 1024, 1024, Wh + 1048576,
                       1024, Kc + (long)b * 2048 * 1024, 1024, bk, bk, 1 << 30, 0,
                       1.0f, 1024, (u >> 3) * 128, (u & 7) * 128);
      } else {  // Vt tile (bias by row)
        const int u2 = u - mt8;
        gemm_body<f16>(As, Bs, Wh + 2097152, 1024, xc + (long)b * 2048 * 1024,
                       1024, Vt + (long)b * 1024 * 2048, 2048, bv, bv, 0, 1, 1.0f,
                       1024, (u2 & 7) * 128, (u2 >> 3) * 128);
      }
    }
  }
}

// ---------------------------------------------------------------- L4 S GEMM (M=64, dense)
// Per batch: 32 m-tiles x (npad/128) n-tiles.
__global__ __launch_bounds__(256, 5) void s_gemm64(
    const f16* __restrict__ Qb, const f16* __restrict__ Kc, f16* __restrict__ Sbuf,
    const int* __restrict__ npad) {
  __shared__ __align__(16) f16 As[64 * 64];
  __shared__ __align__(16) f16 Bs[128 * 64];
  int ku[4], ntl[4];
  int T = 0;
#pragma unroll
  for (int b = 0; b < 4; ++b) {
    ntl[b] = npad[b] >> 7;
    ku[b] = 32 * ntl[b];
    T += ku[b];
  }
  for (int tile = blockIdx.x; tile < T; tile += gridDim.x) {
    int u = tile, b = 0;
    while (u >= ku[b]) { u -= ku[b]; ++b; }
    const int m = u / ntl[b], n = u % ntl[b];
    gemm_body64<f16>(As, Bs, Qb + (long)b * 2048 * 1024, 1024,
                     Kc + (long)b * 2048 * 1024, 1024,
                     Sbuf + (long)b * 2048 * 2048, 2048, 0.03125f, 1024, m * 64,
                     n * 128);
  }
}

// ---------------------------------------------------------------- L5 softmax (compacted)
__global__ LB256 void softmax_c(f16* __restrict__ S, const int* __restrict__ counts,
                                const int* __restrict__ npad) {
  __shared__ float red[4];
  const long r = blockIdx.x;
  const int b = (int)(r >> 11);
  const int nv = counts[b], np = npad[b];
  f16* row = S + r * 2048;
  const int t = threadIdx.x;
  const bool act = (t * 8) < np;

  float v[8];
  float mx = -3.0e38f;
  if (act) {
    f16x8 sv = *(const f16x8*)(row + t * 8);
#pragma unroll
    for (int e = 0; e < 8; ++e) {
      float s = (t * 8 + e < nv) ? (float)sv[e] : -3.0e38f;
      v[e] = s;
      mx = fmaxf(mx, s);
    }
  } else {
#pragma unroll
    for (int e = 0; e < 8; ++e) v[e] = -3.0e38f;
  }
#pragma unroll
  for (int off = 32; off > 0; off >>= 1) mx = fmaxf(mx, __shfl_xor(mx, off, 64));
  if ((t & 63) == 0) red[t >> 6] = mx;
  __syncthreads();
  mx = fmaxf(fmaxf(red[0], red[1]), fmaxf(red[2], red[3]));
  __syncthreads();

  float e[8];
  float sum = 0.f;
#pragma unroll
  for (int it = 0; it < 8; ++it) {
    float ev = (v[it] <= -1.0e38f) ? 0.f : __expf(v[it] - mx);
    e[it] = ev;
    sum += ev;
  }
#pragma unroll
  for (int off = 32; off > 0; off >>= 1) sum += __shfl_xor(sum, off, 64);
  if ((t & 63) == 0) red[t >> 6] = sum;
  __syncthreads();
  sum = red[0] + red[1] + red[2] + red[3];
  if (act) {
    const float inv = 1.f / sum;
    f16x8 ov;
#pragma unroll
    for (int it = 0; it < 8; ++it) ov[it] = (f16)(e[it] * inv);
    *(f16x8*)(row + t * 8) = ov;
  }
}

// ---------------------------------------------------------------- L6 PV GEMM (M=64)
// 1024 tiles exactly: b=tile>>8, m=(tile&255)>>3 (32 of 64 rows), n=tile&7 (8 of 128).
__global__ __launch_bounds__(256, 4) void pv_gemm64(
    const f16* __restrict__ Sbuf, const f16* __restrict__ Vt,
    float* __restrict__ out, const int* __restrict__ npad) {
  __shared__ __align__(16) f16 As[64 * 64];
  __shared__ __align__(16) f16 Bs[128 * 64];
  const int tile = blockIdx.x;
  const int b = tile >> 8, u = tile & 255;
  gemm_body64<float>(As, Bs, Sbuf + (long)b * 2048 * 2048, 2048,
                     Vt + (long)b * 1024 * 2048, 2048, out + (long)b * 2048 * 1024,
                     1024, 1.0f, npad[b], (u >> 3) * 64, (u & 7) * 128);
}

// ---------------------------------------------------------------- launch
extern "C" void kernel_launch(void* const* d_in, const int* in_sizes, int n_in,
                              void* d_out, int out_size, void* d_ws, size_t ws_size,
                              hipStream_t stream) {
  const float* x = (const float*)d_in[0];
  const void* mask = d_in[1];
  const float* Wq = (const float*)d_in[2];
  const float* bq = (const float*)d_in[3];
  const float* Wk = (const float*)d_in[4];
  const float* bk = (const float*)d_in[5];
  const float* Wv = (const float*)d_in[6];
  const float* bv = (const float*)d_in[7];
  float* out = (float*)d_out;

  // Workspace (f16 elems), 118 MB total (proven available in R1).
  f16* xh = (f16*)d_ws;              // 8M  [0,16MB)
  f16* xc = xh + 8388608;            // 8M  [16,32)
  f16* Wh = xc + 8388608;            // 3M  [32,38)  [Wq|Wk|Wv]
  f16* Qb = Wh + 3145728;            // 8M  [38,54)
  f16* Kc = Qb + 8388608;            // 8M  [54,70)
  f16* Vt = Kc + 8388608;            // 8M  [70,86)
  f16* Sbuf = Vt + 8388608;          // 16M [86,118)
  int* sel = (int*)(Sbuf + 16777216);
  int* counts = sel + 8192;
  int* npad = counts + 4;

  prep<<<11268, 256, 0, stream>>>(x, Wq, Wk, Wv, mask, xh, Wh, sel, counts, npad);
  gather_x<<<dim3(512, 4), 256, 0, stream>>>(xh, sel, counts, npad, xc);
  qkvt_gemm<<<1024, 256, 0, stream>>>(xh, xc, Wh, Qb, Kc, Vt, bq, bk, bv, npad);
  s_gemm64<<<1280, 256, 0, stream>>>(Qb, Kc, Sbuf, npad);
  softmax_c<<<8192, 256, 0, stream>>>(Sbuf, counts, npad);
  pv_gemm64<<<1024, 256, 0, stream>>>(Sbuf, Vt, out, npad);
}